// Round 18
// baseline (975.188 us; speedup 1.0000x reference)
//
#include <hip/hip_runtime.h>
#include <hip/hip_bf16.h>

#define IN_F 4096
#define OUT_F 11008

typedef __bf16 bf16_t;
typedef _Float16 f16_t;
typedef f16_t f16x8 __attribute__((ext_vector_type(8)));
typedef f16_t f16x2 __attribute__((ext_vector_type(2)));
typedef u_int32_t u32;
typedef u32 u32x4 __attribute__((ext_vector_type(4)));
typedef bf16_t bf16x8 __attribute__((ext_vector_type(8)));
typedef float f32x4 __attribute__((ext_vector_type(4)));

// ============================ pass 1a: x f32 -> f16 ============================
__global__ __launch_bounds__(256) void cvt_x_kernel(const float* __restrict__ x,
                                                    f16_t* __restrict__ xb) {
    size_t i = ((size_t)blockIdx.x * 256 + threadIdx.x) * 8;
    f32x4 v0 = __builtin_nontemporal_load((const f32x4*)(x + i));
    f32x4 v1 = __builtin_nontemporal_load((const f32x4*)(x + i + 4));
    f16x8 h;
    h[0]=(f16_t)v0[0]; h[1]=(f16_t)v0[1]; h[2]=(f16_t)v0[2]; h[3]=(f16_t)v0[3];
    h[4]=(f16_t)v1[0]; h[5]=(f16_t)v1[1]; h[6]=(f16_t)v1[2]; h[7]=(f16_t)v1[3];
    *(f16x8*)(xb + i) = h;
}

// ========== pass 2: 256x256 8-phase GEMM, B raw-4-bit LDS, f16, ONE-AHEAD ==========
// R17 = R16 numerics (packed f16 dequant, proven) + N-MAJOR quadrant order
// {M0N01, M1N01, M0N23, M1N23} which makes one-phase-ahead fit registers:
//  - single bP[4] B-set (16 regs, was 32): B pair has contiguous 2-phase
//    lifetime; one DEQ/pair/K-tile placed POST-MFMA in ph2/4/6/8 (VALU runs
//    while MFMA pipe drains). Same dequant op count as R16.
//  - two A-sets aX/aY (64 regs): reads 8/phase at ph1/ph4/ph5/ph8, every
//    MFMA's operands ds_read >=1 phase ahead (the m201 mechanism).
//    Post-wait reads (ph4 aX<-buf1, ph8 aX<-buf0') placed AFTER their
//    confirming vmcnt.
//  Stage ring + vmcnt identical to R15/R16 (proven race-free):
//    A@ph1(A11),ph4(A00),ph5(A01),ph8(A10); B@ph1(buf0,T2),ph5(buf1,T3);
//    scales ph2; vmcnt(10)@ph4 confirms T1-A; vmcnt(2)@ph8 confirms T2.
//  Register tally ~120 < 128 arch cap -> no spill (WRITE must be 352,256 KB).

#define NI (IN_F / 128)   // 32 iterations = 32 groups, 64 K-tiles

__global__ __launch_bounds__(512, 2) void gemm_q4(const f16_t* __restrict__ A,
                                                  const int* __restrict__ qweight,
                                                  const float* __restrict__ scales,
                                                  const int* __restrict__ qzeros,
                                                  float* __restrict__ C) {
    __shared__ __align__(16) f16_t smemA[2 * 2 * 128 * 64];   // 64 KiB
    __shared__ __align__(16) u32   smemB[2 * 2048];           // 16 KiB (4-bit B)

    const int tid  = threadIdx.x;
    const int lane = tid & 63;
    const int wid  = tid >> 6;      // 0..7
    const int wr   = wid >> 2;      // 0..1  (M half)
    const int wc   = wid & 3;       // 0..3  (N quarter)

    // bijective XCD swizzle: nwg = 1376 = 8*172
    const int bid = blockIdx.x;
    const int swz = (bid & 7) * 172 + (bid >> 3);
    const int bx = swz % 43;
    const int by = swz / 43;
    const int m0 = by * 256;
    const int n0 = bx * 256;

    // A staging map: linear LDS slot -> inverse-swizzled global position
    int lr0, kb0, lr1, kb1;
    {
        int L0 = tid * 16;
        int p0 = L0 ^ (((L0 >> 7) & 7) << 4);
        lr0 = p0 >> 7; kb0 = (p0 & 127) >> 1;
        int L1 = (512 + tid) * 16;
        int p1 = L1 ^ (((L1 >> 7) & 7) << 4);
        lr1 = p1 >> 7; kb1 = (p1 & 127) >> 1;
    }

    // A fragment-read swizzled column byte offsets within a 128B row
    const int xm = (lane & 7) << 4;
    const int arow = lane & 15;
    int colk[2];
    #pragma unroll
    for (int ks = 0; ks < 2; ++ks)
        colk[ks] = ((ks * 64) + ((lane >> 4) * 16)) ^ xm;

    // B-side: per-lane LDS word base; per-thread stage source pointer
    const int ncol = n0 + wc * 64 + (lane & 15);
    const u32* bw = smemB + (wc * 512 + (lane >> 4) * 16 + (lane & 15));
    const int kwS  = (tid >> 2) & 7;
    const int colS = (tid >> 5) * 16 + (tid & 3) * 4;
    const u32* qB = (const u32*)qweight + (size_t)kwS * OUT_F + n0 + colS;
    const int zsh = (lane & 7) * 4;

#define STAGE_A(buf, half, koff)                                                           \
    do {                                                                                   \
        const f16_t* g0_ = A + (size_t)(m0 + (half) * 128 + lr0) * IN_F + (koff) + kb0;    \
        __builtin_amdgcn_global_load_lds(                                                  \
            (const __attribute__((address_space(1))) u32*)g0_,                             \
            (__attribute__((address_space(3))) u32*)((char*)smemA + (buf) * 32768 +        \
                                                     (half) * 16384 + wid * 1024),         \
            16, 0, 0);                                                                     \
        const f16_t* g1_ = A + (size_t)(m0 + (half) * 128 + lr1) * IN_F + (koff) + kb1;    \
        __builtin_amdgcn_global_load_lds(                                                  \
            (const __attribute__((address_space(1))) u32*)g1_,                             \
            (__attribute__((address_space(3))) u32*)((char*)smemA + (buf) * 32768 +        \
                                                     (half) * 16384 + 8192 + wid * 1024),  \
            16, 0, 0);                                                                     \
    } while (0)

// B stage: one width-16 load/thread; dest linear; src = qweight row (ktrow+kwS)
#define STAGE_B(buf, ktrow)                                                                \
    __builtin_amdgcn_global_load_lds(                                                      \
        (const __attribute__((address_space(1))) u32*)(qB + (size_t)(ktrow) * OUT_F),      \
        (__attribute__((address_space(3))) u32*)((char*)smemB + (buf) * 8192 + tid * 16),  \
        16, 0, 0)

// 8 ds_read_b128 -> dst : A fragments (4 m-tiles x 2 k-slices)
#define RD_A(dst, buf, mbase)                                                              \
    _Pragma("unroll") for (int mm = 0; mm < 4; ++mm)                                       \
    _Pragma("unroll") for (int ks = 0; ks < 2; ++ks)                                       \
        dst[mm * 2 + ks] = *(const f16x8*)((const char*)smemA + (buf) * 32768 +            \
            wr * 16384 + (((mbase) + mm) * 16 + arow) * 128 + colk[ks]);

// 8 ds_read_b32 (base + compile-time imm): all 4 n-tiles x 2 ks of one buffer
#define RD_W(buf)                                                                          \
    _Pragma("unroll") for (int nt = 0; nt < 4; ++nt)                                       \
    _Pragma("unroll") for (int ks = 0; ks < 2; ++ks)                                       \
        w[nt * 2 + ks] = bw[(buf) * 2048 + nt * 128 + ks * 64];

// packed-f16 dequant of one B pair (n-tiles nt0..nt0+1, 2 ks) into bP
#define DEQ(nt0)                                                                           \
    _Pragma("unroll") for (int nn = 0; nn < 2; ++nn)                                       \
    _Pragma("unroll") for (int ks = 0; ks < 2; ++ks) {                                     \
        const u32 wv_ = w[((nt0) + nn) * 2 + ks];                                          \
        const u32 od_ = wv_ >> 4;                                                          \
        const f16x2 zp_ = zh[(nt0) + nn];                                                  \
        const f16x2 sp_ = sh[(nt0) + nn];                                                  \
        u32x4 hw_;                                                                         \
        _Pragma("unroll") for (int p = 0; p < 4; ++p) {                                    \
            u32 t_ = __builtin_amdgcn_perm(od_, wv_,                                       \
                         0x0C000C00u | (u32)p | ((u32)(4 + p) << 16));                     \
            u32 u_ = (t_ & 0x000F000Fu) | 0x64006400u;                                     \
            f16x2 b_ = (__builtin_bit_cast(f16x2, u_) - zp_) * sp_;                        \
            hw_[p] = __builtin_bit_cast(u32, b_);                                          \
        }                                                                                  \
        bP[nn * 2 + ks] = __builtin_bit_cast(f16x8, hw_);                                  \
    }

// 16 MFMA: one quadrant (4 m x 2 n x 2 ks); B always from bP
#define MFMA_Q(aArr, mbase, nbase)                                                         \
    __builtin_amdgcn_s_setprio(1);                                                         \
    _Pragma("unroll") for (int mm = 0; mm < 4; ++mm)                                       \
    _Pragma("unroll") for (int nn = 0; nn < 2; ++nn)                                       \
    _Pragma("unroll") for (int ks = 0; ks < 2; ++ks)                                       \
        acc[(mbase) + mm][(nbase) + nn] = __builtin_amdgcn_mfma_f32_16x16x32_f16(          \
            aArr[mm * 2 + ks], bP[nn * 2 + ks], acc[(mbase) + mm][(nbase) + nn],           \
            0, 0, 0);                                                                      \
    __builtin_amdgcn_s_setprio(0);

// per-group packed constants: zh = f16x2(1025+z), sh = f16x2(s)
#define CVT_SCALES()                                                                       \
    _Pragma("unroll") for (int nt = 0; nt < 4; ++nt) {                                     \
        u32 zb_ = 0x6401u + ((zraw[nt] >> zsh) & 0xFu);                                    \
        zb_ |= zb_ << 16;                                                                  \
        zh[nt] = __builtin_bit_cast(f16x2, zb_);                                           \
        u32 sb_ = (u32)__builtin_bit_cast(unsigned short, (f16_t)sraw[nt]);                \
        sb_ |= sb_ << 16;                                                                  \
        sh[nt] = __builtin_bit_cast(f16x2, sb_);                                           \
    }

#define SCHED0() __builtin_amdgcn_sched_barrier(0)
#define BAR() do { SCHED0(); __builtin_amdgcn_s_barrier(); } while (0)
#define VMCNT10() asm volatile("s_waitcnt vmcnt(10)" ::: "memory")
#define VMCNT2()  asm volatile("s_waitcnt vmcnt(2)"  ::: "memory")
#define VMCNT0()  asm volatile("s_waitcnt vmcnt(0)"  ::: "memory")

    f32x4 acc[8][4];
    #pragma unroll
    for (int m = 0; m < 8; ++m)
        #pragma unroll
        for (int n = 0; n < 4; ++n)
            acc[m][n] = (f32x4)0.0f;

    f16x8 aX[8], aY[8], bP[4];
    u32   w[8];
    f16x2 zh[4], sh[4];
    float sraw[4]; u32 zraw[4];

    // ---- prologue: stage T0(A,B), T1(B), T1-A10; drain; scales g0; deq b01(T0);
    //      pre-read aX(M0,buf0); barrier (B-buf0 WAR guard).
    STAGE_A(0, 0, 0); STAGE_A(0, 1, 0);
    STAGE_B(0, 0);
    STAGE_B(1, 8);
    STAGE_A(1, 0, 64);
    VMCNT0();
    BAR();
    #pragma unroll
    for (int nt = 0; nt < 4; ++nt) {
        sraw[nt] = scales[ncol + nt * 16];
        zraw[nt] = ((const u32*)qzeros)[(ncol >> 3) + nt * 2];
    }
    CVT_SCALES();
    RD_W(0);
    DEQ(0);                  // bP = b01(T0)
    RD_A(aX, 0, 0);          // M0, buf0 (the "prev-ph8" read)
    BAR();

    for (int i = 0; i < NI; ++i) {
        const int  kc = i * 128;        // T0 in buf0; T1 = kc+64 in buf1
        const int  kn = kc + 128;       // T2 in buf0; T3 = kn+64 in buf1
        const bool nl = (i + 1 < NI);

        // ph1 (M0,N01,buf0 via aX,bP=b01): read aY<-M1,buf0; stage A11(T1), B0(T2)
        RD_A(aY, 0, 4);
        STAGE_A(1, 1, kc + 64);
        if (nl) STAGE_B(0, kn >> 3);
        MFMA_Q(aX, 0, 0);
        BAR();
        // ph2 (M1,N01): scale raws g(i+1); MFMA; then deq bP<-b23(T0)
        if (nl) {
            #pragma unroll
            for (int nt = 0; nt < 4; ++nt) {
                sraw[nt] = scales[ncol + (i + 1) * OUT_F + nt * 16];
                zraw[nt] = ((const u32*)qzeros)[(ncol >> 3) + (i + 1) * (OUT_F / 8) + nt * 2];
            }
        }
        MFMA_Q(aY, 4, 0);
        DEQ(2);
        BAR();
        // ph3 (M0,N23): w <- T1 words
        RD_W(1);
        MFMA_Q(aX, 0, 2);
        BAR();
        // ph4 (M1,N23): stage A00(T2); MFMA; vmcnt(10) -> T1-A complete;
        //      read aX<-M0,buf1 (after wait); deq bP<-b01(T1)
        if (nl) STAGE_A(0, 0, kn);
        MFMA_Q(aY, 4, 2);
        if (nl) VMCNT10(); else VMCNT0();
        RD_A(aX, 1, 0);
        DEQ(0);
        BAR();
        // ph5 (M0,N01,buf1): read aY<-M1,buf1; stage A01(T2), B1(T3)
        RD_A(aY, 1, 4);
        if (nl) { STAGE_A(0, 1, kn); STAGE_B(1, (kn + 64) >> 3); }
        MFMA_Q(aX, 0, 0);
        BAR();
        // ph6 (M1,N01): MFMA; deq bP<-b23(T1)
        MFMA_Q(aY, 4, 0);
        DEQ(2);
        BAR();
        // ph7 (M0,N23): convert g(i+1) packed scales
        if (nl) CVT_SCALES();
        MFMA_Q(aX, 0, 2);
        BAR();
        // ph8 (M1,N23): stage A10(T3); MFMA; vmcnt(2) -> T2 published;
        //      read aX<-M0,buf0-next + w<-T2 (after wait); deq bP<-b01(T2,g i+1)
        if (nl) STAGE_A(1, 0, kn + 64);
        MFMA_Q(aY, 4, 2);
        if (nl) VMCNT2(); else VMCNT0();
        if (nl) {
            RD_A(aX, 0, 0);
            RD_W(0);
            DEQ(0);
        }
        BAR();
    }

    // epilogue: C/D layout col = lane&15, row = (lane>>4)*4 + r
    const int cn  = lane & 15;
    const int cr4 = (lane >> 4) * 4;
    #pragma unroll
    for (int m = 0; m < 8; ++m) {
        #pragma unroll
        for (int r = 0; r < 4; ++r) {
            const int grow = m0 + wr * 128 + m * 16 + cr4 + r;
            float* orow = C + (size_t)grow * OUT_F + n0 + wc * 64 + cn;
            #pragma unroll
            for (int n = 0; n < 4; ++n)
                orow[n * 16] = acc[m][n][r];
        }
    }
}

// ===================== fallback: fused kernel (R0 structure) =====================
#define BMf 128
#define BNf 128
#define BKf 32
#define LDPF 40

__global__ __launch_bounds__(256, 2) void gptq_gemm_fused(
    const float* __restrict__ x, const int* __restrict__ qweight,
    const float* __restrict__ scales, const int* __restrict__ qzeros,
    float* __restrict__ out)
{
    __shared__ bf16_t As[BMf * LDPF];
    __shared__ bf16_t Bs[BNf * LDPF];
    const int tid = threadIdx.x, lane = tid & 63, wid = tid >> 6;
    const int wr = wid >> 1, wc = wid & 1;
    const int m0 = blockIdx.y * BMf, n0 = blockIdx.x * BNf;
    const int a_row = tid >> 2, a_slot = tid & 3;
    const int b_k8l = tid >> 7, b_n = tid & 127;

    f32x4 acc[4][4];
    #pragma unroll
    for (int i = 0; i < 4; ++i)
        #pragma unroll
        for (int j = 0; j < 4; ++j) acc[i][j] = (f32x4)0.0f;

    for (int kt = 0; kt < IN_F / BKf; ++kt) {
        const int k0 = kt * BKf;
        const int g  = k0 >> 7;
        __syncthreads();
        #pragma unroll
        for (int p = 0; p < 2; ++p) {
            const int row = a_row + p * 64;
            const float* src = x + (size_t)(m0 + row) * IN_F + k0 + a_slot * 8;
            f32x4 v0 = *(const f32x4*)src;
            f32x4 v1 = *(const f32x4*)(src + 4);
            bf16x8 h;
            h[0]=(bf16_t)v0[0]; h[1]=(bf16_t)v0[1]; h[2]=(bf16_t)v0[2]; h[3]=(bf16_t)v0[3];
            h[4]=(bf16_t)v1[0]; h[5]=(bf16_t)v1[1]; h[6]=(bf16_t)v1[2]; h[7]=(bf16_t)v1[3];
            *(bf16x8*)(&As[row * LDPF + a_slot * 8]) = h;
        }
        {
            const int gn = n0 + b_n;
            const float s  = scales[(size_t)g * OUT_F + gn];
            const int   zw = qzeros[(size_t)g * (OUT_F / 8) + (gn >> 3)];
            const float sz = s * (float)(((zw >> ((gn & 7) * 4)) & 0xF) + 1);
            #pragma unroll
            for (int p = 0; p < 2; ++p) {
                const int k8l = b_k8l + p * 2;
                const int w = qweight[(size_t)(k0 / 8 + k8l) * OUT_F + gn];
                bf16x8 h;
                #pragma unroll
                for (int j = 0; j < 8; ++j)
                    h[j] = (bf16_t)fmaf((float)((w >> (4 * j)) & 0xF), s, -sz);
                *(bf16x8*)(&Bs[b_n * LDPF + k8l * 8]) = h;
            }
        }
        __syncthreads();
        bf16x8 af[4], bfr[4];
        #pragma unroll
        for (int m = 0; m < 4; ++m)
            af[m] = *(const bf16x8*)(&As[(wr * 64 + m * 16 + (lane & 15)) * LDPF + (lane >> 4) * 8]);
        #pragma unroll
        for (int n = 0; n < 4; ++n)
            bfr[n] = *(const bf16x8*)(&Bs[(wc * 64 + n * 16 + (lane & 15)) * LDPF + (lane >> 4) * 8]);
        #pragma unroll
        for (int m = 0; m < 4; ++m)
            #pragma unroll
            for (int n = 0; n < 4; ++n)
                acc[m][n] = __builtin_amdgcn_mfma_f32_16x16x32_bf16(af[m], bfr[n], acc[m][n], 0, 0, 0);
    }
    const int cn = lane & 15, cr4 = (lane >> 4) * 4;
    #pragma unroll
    for (int m = 0; m < 4; ++m)
        #pragma unroll
        for (int r = 0; r < 4; ++r) {
            const int grow = m0 + wr * 64 + m * 16 + cr4 + r;
            float* orow = out + (size_t)grow * OUT_F + n0 + wc * 64 + cn;
            #pragma unroll
            for (int n = 0; n < 4; ++n) orow[n * 16] = acc[m][n][r];
        }
}

extern "C" void kernel_launch(void* const* d_in, const int* in_sizes, int n_in,
                              void* d_out, int out_size, void* d_ws, size_t ws_size,
                              hipStream_t stream) {
    const float* x       = (const float*)d_in[0];
    const int*   qweight = (const int*)d_in[1];
    const float* scales  = (const float*)d_in[2];
    const int*   qzeros  = (const int*)d_in[3];
    float* out = (float*)d_out;

    const int M = in_sizes[0] / IN_F;                       // 8192
    const size_t xb_bytes = (size_t)M * IN_F * 2;           // 67 MB

    if (ws_size >= xb_bytes && (M % 256) == 0) {
        f16_t* xb = (f16_t*)d_ws;
        cvt_x_kernel<<<dim3((M * IN_F) / (256 * 8)), dim3(256), 0, stream>>>(x, xb);
        const int nwg = (OUT_F / 256) * (M / 256);          // 43*32 = 1376
        gemm_q4<<<dim3(nwg), dim3(512), 0, stream>>>(xb, qweight, scales, qzeros, out);
    } else {
        gptq_gemm_fused<<<dim3(OUT_F / BNf, M / BMf), dim3(256), 0, stream>>>(
            x, qweight, scales, qzeros, out);
    }
}